// Round 1
// baseline (198.131 us; speedup 1.0000x reference)
//
#include <hip/hip_runtime.h>
#include <cfloat>

#define BATCH 4
#define CDESC 32
#define N0 4096
#define N1 512
#define CHUNK0 1024

// ---------------- resize pass 1: filter the w (x) dimension ----------------
// in : [B*3][64][64][64]   out: [B*3][64][64][S]
template<int S, int R>
__global__ void resize_pass1(const float* __restrict__ in0, const float* __restrict__ in1,
                             float* __restrict__ out0, float* __restrict__ out1) {
    const float* in = blockIdx.y ? in1 : in0;
    float* out      = blockIdx.y ? out1 : out0;
    int idx = blockIdx.x * 256 + threadIdx.x;      // total = B*3*64*64*S (exact)
    int xo = idx & (S - 1);
    int r  = idx / S;
    int y  = r & 63; r >>= 6;
    int z  = r & 63; r >>= 6;
    int bc = r;                                    // 0..11
    const float* row = in + (((bc * 64) + z) * 64 + y) * 64;
    constexpr int KW = 2 * R;
    int j0 = R * xo - R / 2;
    float sum = 0.f, wsum = 0.f;
#pragma unroll
    for (int t = 0; t < KW; ++t) {
        int j = j0 + t;
        float w = 1.f - fabsf((float)t - ((float)R - 0.5f)) / (float)R;
        if (j >= 0 && j < 64) { sum = fmaf(w, row[j], sum); wsum += w; }
    }
    out[idx] = sum / wsum;
}

// ---------------- resize pass 2: filter h (y) and d (z), emit point + |p|^2 ----------------
// in : [B*3][64][64][S]   out: pts[b][n] = (x,y,z,|p|^2), n = (z*S+y)*S+x
template<int S, int R>
__global__ void resize_pass2(const float* __restrict__ t0, const float* __restrict__ t1,
                             float4* __restrict__ p0, float4* __restrict__ p1) {
    const float* t = blockIdx.y ? t1 : t0;
    float4* pts    = blockIdx.y ? p1 : p0;
    int idx = blockIdx.x * 256 + threadIdx.x;      // total = B*S^3 (exact)
    int n = idx & (S * S * S - 1);
    int b = idx / (S * S * S);
    int x = n & (S - 1);
    int y = (n / S) & (S - 1);
    int z = n / (S * S);
    constexpr int KW = 2 * R;
    constexpr int CS = 64 * 64 * S;                // channel stride in t1
    int jy0 = R * y - R / 2;
    int jz0 = R * z - R / 2;
    float wys = 0.f, wzs = 0.f;
#pragma unroll
    for (int tt = 0; tt < KW; ++tt) {
        float w = 1.f - fabsf((float)tt - ((float)R - 0.5f)) / (float)R;
        int jy = jy0 + tt; if (jy >= 0 && jy < 64) wys += w;
        int jz = jz0 + tt; if (jz >= 0 && jz < 64) wzs += w;
    }
    float inv = 1.f / (wys * wzs);
    float a0 = 0.f, a1 = 0.f, a2 = 0.f;
#pragma unroll 1
    for (int tz = 0; tz < KW; ++tz) {
        int jz = jz0 + tz;
        if (jz < 0 || jz >= 64) continue;
        float wz_ = 1.f - fabsf((float)tz - ((float)R - 0.5f)) / (float)R;
        const float* bz = t + (size_t)b * 3 * CS + jz * (64 * S) + x;
#pragma unroll
        for (int ty = 0; ty < KW; ++ty) {
            int jy = jy0 + ty;
            if (jy < 0 || jy >= 64) continue;
            float w = wz_ * (1.f - fabsf((float)ty - ((float)R - 0.5f)) / (float)R);
            const float* p = bz + jy * S;
            a0 = fmaf(w, p[0],      a0);
            a1 = fmaf(w, p[CS],     a1);
            a2 = fmaf(w, p[2 * CS], a2);
        }
    }
    a0 *= inv; a1 *= inv; a2 *= inv;
    pts[idx] = make_float4(a0, a1, a2, a0 * a0 + a1 * a1 + a2 * a2);
}

// ---------------- stage-0 argmin, m split in 4 chunks of 1024 ----------------
// argmin_m (|a|^2 + |b|^2 - 2ab) == argmin_m (|b|^2 - 2ab); strict < keeps first min.
__global__ void argmin_stage0(const float4* __restrict__ src_pts, const float4* __restrict__ tgt_pts,
                              float2* __restrict__ partial) {
    __shared__ float4 sm[CHUNK0];
    int tid = threadIdx.x;
    int ntile = blockIdx.x, chunk = blockIdx.y, b = blockIdx.z;
    const float4* tp = tgt_pts + b * N0 + chunk * CHUNK0;
    for (int i = tid; i < CHUNK0; i += 256) sm[i] = tp[i];
    __syncthreads();
    int n = ntile * 256 + tid;
    float4 p = src_pts[b * N0 + n];
    float best = FLT_MAX; int bi = 0;
#pragma unroll 8
    for (int m = 0; m < CHUNK0; ++m) {
        float4 q = sm[m];                          // broadcast LDS read, conflict-free
        float d = fmaf(-2.f, fmaf(p.x, q.x, fmaf(p.y, q.y, p.z * q.z)), q.w);
        if (d < best) { best = d; bi = m; }
    }
    partial[(size_t)(b * N0 + n) * 4 + chunk] = make_float2(best, __int_as_float(chunk * CHUNK0 + bi));
}

__device__ inline void wave_reduce_atomic(float v, float* acc) {
#pragma unroll
    for (int off = 32; off > 0; off >>= 1) v += __shfl_down(v, off, 64);
    if ((threadIdx.x & 63) == 0) atomicAdd(acc, v);
}

// ---------------- stage-0: combine chunks, gather descriptor, cosine, reduce ----------------
__global__ void cos_stage0(const float2* __restrict__ partial,
                           const float* __restrict__ sd, const float* __restrict__ td,
                           float* __restrict__ acc) {
    int gid = blockIdx.x * 256 + threadIdx.x;      // 0..16383
    int b = gid >> 12, n = gid & (N0 - 1);
    const float2* pp = partial + (size_t)gid * 4;
    float2 e = pp[0];
    float2 e1 = pp[1]; if (e1.x < e.x) e = e1;     // ascending chunk order + strict <
    float2 e2 = pp[2]; if (e2.x < e.x) e = e2;     //   == jnp.argmin first-min tiebreak
    float2 e3 = pp[3]; if (e3.x < e.x) e = e3;
    int nearest = __float_as_int(e.y);
    const float* s = sd + (size_t)b * CDESC * N0 + n;
    const float* t = td + (size_t)b * CDESC * N0 + nearest;
    float num = 0.f, s2 = 0.f, t2 = 0.f;
#pragma unroll
    for (int c = 0; c < CDESC; ++c) {
        float a = s[c * N0], g = t[c * N0];
        num = fmaf(a, g, num); s2 = fmaf(a, a, s2); t2 = fmaf(g, g, t2);
    }
    float denom = fmaxf(sqrtf(s2), 1e-8f) * fmaxf(sqrtf(t2), 1e-8f);
    wave_reduce_atomic(num / denom, acc);
}

// ---------------- stage-1: fused argmin (full 512 scan) + cosine + reduce ----------------
__global__ void stage1_all(const float4* __restrict__ src_pts, const float4* __restrict__ tgt_pts,
                           const float* __restrict__ sd, const float* __restrict__ td,
                           float* __restrict__ acc) {
    __shared__ float4 sm[N1];
    int tid = threadIdx.x;
    int b = blockIdx.y;
    const float4* tp = tgt_pts + b * N1;
    for (int i = tid; i < N1; i += 256) sm[i] = tp[i];
    __syncthreads();
    int n = blockIdx.x * 256 + tid;
    float4 p = src_pts[b * N1 + n];
    float best = FLT_MAX; int bi = 0;
#pragma unroll 8
    for (int m = 0; m < N1; ++m) {
        float4 q = sm[m];
        float d = fmaf(-2.f, fmaf(p.x, q.x, fmaf(p.y, q.y, p.z * q.z)), q.w);
        if (d < best) { best = d; bi = m; }
    }
    const float* s = sd + (size_t)b * CDESC * N1 + n;
    const float* t = td + (size_t)b * CDESC * N1 + bi;
    float num = 0.f, s2 = 0.f, t2 = 0.f;
#pragma unroll
    for (int c = 0; c < CDESC; ++c) {
        float a = s[c * N1], g = t[c * N1];
        num = fmaf(a, g, num); s2 = fmaf(a, a, s2); t2 = fmaf(g, g, t2);
    }
    float denom = fmaxf(sqrtf(s2), 1e-8f) * fmaxf(sqrtf(t2), 1e-8f);
    wave_reduce_atomic(num / denom, acc);
}

__global__ void zero_acc(float* acc) { if (threadIdx.x < 2) acc[threadIdx.x] = 0.f; }

__global__ void finalize_k(const float* __restrict__ acc, float* __restrict__ out) {
    // loss = (l0 + l1)/2 = 1 - 0.5*(mean0 + mean1)
    out[0] = 1.f - 0.5f * (acc[0] * (1.f / 16384.f) + acc[1] * (1.f / 2048.f));
}

extern "C" void kernel_launch(void* const* d_in, const int* in_sizes, int n_in,
                              void* d_out, int out_size, void* d_ws, size_t ws_size,
                              hipStream_t stream) {
    const float* c_src = (const float*)d_in[0];   // [4,3,64,64,64]
    const float* c_tgt = (const float*)d_in[1];
    const float* sd0   = (const float*)d_in[2];   // [4,32,16,16,16]
    const float* td0   = (const float*)d_in[3];
    const float* sd1   = (const float*)d_in[4];   // [4,32,8,8,8]
    const float* td1   = (const float*)d_in[5];
    float* out = (float*)d_out;

    char* ws = (char*)d_ws;
    float*  acc  = (float*)ws;                         // 2 floats (pad to 256 B)
    float*  t1a  = (float*)(ws + 256);                 // 786432 floats (3.0 MB) max
    float*  t1b  = t1a + 786432;
    float4* ps0  = (float4*)(t1b + 786432);            // 16384 float4
    float4* pt0  = ps0 + 16384;
    float4* ps1  = pt0 + 16384;                        // 2048 float4
    float4* pt1  = ps1 + 2048;
    float2* part = (float2*)(pt1 + 2048);              // 65536 float2 (512 KB)

    zero_acc<<<1, 64, 0, stream>>>(acc);

    // stage 0 resize: 64^3 -> 16^3 (ratio 4)
    resize_pass1<16, 4><<<dim3(3072, 2), 256, 0, stream>>>(c_src, c_tgt, t1a, t1b);
    resize_pass2<16, 4><<<dim3(64, 2),   256, 0, stream>>>(t1a, t1b, ps0, pt0);
    // stage 1 resize: 64^3 -> 8^3 (ratio 8), reuse t1 buffers
    resize_pass1<8, 8><<<dim3(1536, 2), 256, 0, stream>>>(c_src, c_tgt, t1a, t1b);
    resize_pass2<8, 8><<<dim3(8, 2),    256, 0, stream>>>(t1a, t1b, ps1, pt1);

    // stage 0: chunked argmin (4 b x 4 chunks x 16 n-tiles = 256 blocks), then cos+reduce
    argmin_stage0<<<dim3(16, 4, 4), 256, 0, stream>>>(ps0, pt0, part);
    cos_stage0<<<64, 256, 0, stream>>>(part, sd0, td0, acc + 0);

    // stage 1: fused
    stage1_all<<<dim3(2, 4), 256, 0, stream>>>(ps1, pt1, sd1, td1, acc + 1);

    finalize_k<<<1, 1, 0, stream>>>(acc, out);
}

// Round 2
// 158.798 us; speedup vs baseline: 1.2477x; 1.2477x over previous
//
#include <hip/hip_runtime.h>
#include <cfloat>

#define CDESC 32
#define N0 4096
#define N1 512
#define CHUNK0 1024

// ---------------- pass-1 body: filter the w (x) dimension ----------------
// in : [B*3][64][64][64]   out: [B*3][64][64][S]
template<int S, int R>
__device__ __forceinline__ void pass1_body(const float* __restrict__ in,
                                           float* __restrict__ out, int idx) {
    int xo = idx & (S - 1);
    int r  = idx / S;
    int y  = r & 63; r >>= 6;
    int z  = r & 63; r >>= 6;
    int bc = r;                                    // 0..11
    const float* row = in + (((bc * 64) + z) * 64 + y) * 64;
    constexpr int KW = 2 * R;
    int j0 = R * xo - R / 2;
    float sum = 0.f, wsum = 0.f;
#pragma unroll
    for (int t = 0; t < KW; ++t) {
        int j = j0 + t;
        float w = 1.f - fabsf((float)t - ((float)R - 0.5f)) / (float)R;
        if (j >= 0 && j < 64) { sum = fmaf(w, row[j], sum); wsum += w; }
    }
    out[idx] = sum / wsum;
}

// K1: both stages' x-filter in one kernel; also zero the accumulators.
__global__ void pass1_both(const float* __restrict__ csrc, const float* __restrict__ ctgt,
                           float* __restrict__ t16a, float* __restrict__ t16b,
                           float* __restrict__ t8a,  float* __restrict__ t8b,
                           float* __restrict__ acc) {
    const float* in = blockIdx.y ? ctgt : csrc;
    if (blockIdx.x < 3072) {
        float* out = blockIdx.y ? t16b : t16a;
        pass1_body<16, 4>(in, out, blockIdx.x * 256 + threadIdx.x);
    } else {
        float* out = blockIdx.y ? t8b : t8a;
        pass1_body<8, 8>(in, out, (blockIdx.x - 3072) * 256 + threadIdx.x);
    }
    if (blockIdx.x == 0 && blockIdx.y == 0 && threadIdx.x < 4) acc[threadIdx.x] = 0.f;
}

// ---------------- pass-2 body: filter h (y) and d (z), emit point + |p|^2 ----------------
template<int S, int R>
__device__ __forceinline__ void pass2_body(const float* __restrict__ t,
                                           float4* __restrict__ pts, int idx) {
    int n = idx & (S * S * S - 1);
    int b = idx / (S * S * S);
    int x = n & (S - 1);
    int y = (n / S) & (S - 1);
    int z = n / (S * S);
    constexpr int KW = 2 * R;
    constexpr int CS = 64 * 64 * S;
    int jy0 = R * y - R / 2;
    int jz0 = R * z - R / 2;
    float wys = 0.f, wzs = 0.f;
#pragma unroll
    for (int tt = 0; tt < KW; ++tt) {
        float w = 1.f - fabsf((float)tt - ((float)R - 0.5f)) / (float)R;
        int jy = jy0 + tt; if (jy >= 0 && jy < 64) wys += w;
        int jz = jz0 + tt; if (jz >= 0 && jz < 64) wzs += w;
    }
    float inv = 1.f / (wys * wzs);
    float a0 = 0.f, a1 = 0.f, a2 = 0.f;
#pragma unroll 1
    for (int tz = 0; tz < KW; ++tz) {
        int jz = jz0 + tz;
        if (jz < 0 || jz >= 64) continue;
        float wz_ = 1.f - fabsf((float)tz - ((float)R - 0.5f)) / (float)R;
        const float* bz = t + (size_t)b * 3 * CS + jz * (64 * S) + x;
#pragma unroll
        for (int ty = 0; ty < KW; ++ty) {
            int jy = jy0 + ty;
            if (jy < 0 || jy >= 64) continue;
            float w = wz_ * (1.f - fabsf((float)ty - ((float)R - 0.5f)) / (float)R);
            const float* p = bz + jy * S;
            a0 = fmaf(w, p[0],      a0);
            a1 = fmaf(w, p[CS],     a1);
            a2 = fmaf(w, p[2 * CS], a2);
        }
    }
    a0 *= inv; a1 *= inv; a2 *= inv;
    pts[idx] = make_float4(a0, a1, a2, a0 * a0 + a1 * a1 + a2 * a2);
}

// K2: both stages' y/z-filter.
__global__ void pass2_both(const float* __restrict__ t16a, const float* __restrict__ t16b,
                           const float* __restrict__ t8a,  const float* __restrict__ t8b,
                           float4* __restrict__ ps0, float4* __restrict__ pt0,
                           float4* __restrict__ ps1, float4* __restrict__ pt1) {
    if (blockIdx.x < 64) {
        const float* t = blockIdx.y ? t16b : t16a;
        float4* pts    = blockIdx.y ? pt0  : ps0;
        pass2_body<16, 4>(t, pts, blockIdx.x * 256 + threadIdx.x);
    } else {
        const float* t = blockIdx.y ? t8b : t8a;
        float4* pts    = blockIdx.y ? pt1  : ps1;
        pass2_body<8, 8>(t, pts, (blockIdx.x - 64) * 256 + threadIdx.x);
    }
}

__device__ __forceinline__ void wave_reduce_atomic(float v, float* acc) {
#pragma unroll
    for (int off = 32; off > 0; off >>= 1) v += __shfl_down(v, off, 64);
    if ((threadIdx.x & 63) == 0) atomicAdd(acc, v);
}

// K3: stage-0 chunked argmin (blocks 0..255) + fully-fused stage-1 (blocks 256..263).
// Targets staged to LDS pre-scaled as (-2x,-2y,-2z,|q|^2): d = fma(px,qx',fma(py,qy',fma(pz,qz',qw))).
// Strict < keeps first min == jnp.argmin tie-break.
__global__ void argmin_plus_stage1(const float4* __restrict__ ps0, const float4* __restrict__ pt0,
                                   float2* __restrict__ partial,
                                   const float4* __restrict__ ps1, const float4* __restrict__ pt1,
                                   const float* __restrict__ sd1, const float* __restrict__ td1,
                                   float* __restrict__ acc) {
    __shared__ float4 sm[CHUNK0];
    int tid = threadIdx.x;
    if (blockIdx.x < 256) {
        int bx = blockIdx.x;
        int ntile = bx & 15, chunk = (bx >> 4) & 3, b = bx >> 6;
        const float4* tp = pt0 + b * N0 + chunk * CHUNK0;
        for (int i = tid; i < CHUNK0; i += 256) {
            float4 q = tp[i];
            sm[i] = make_float4(-2.f * q.x, -2.f * q.y, -2.f * q.z, q.w);
        }
        __syncthreads();
        int n = ntile * 256 + tid;
        float4 p = ps0[b * N0 + n];
        float best = FLT_MAX; int bi = 0;
#pragma unroll 8
        for (int m = 0; m < CHUNK0; ++m) {
            float4 q = sm[m];                      // broadcast LDS read, conflict-free
            float d = fmaf(p.x, q.x, fmaf(p.y, q.y, fmaf(p.z, q.z, q.w)));
            if (d < best) { best = d; bi = m; }
        }
        partial[(size_t)(b * N0 + n) * 4 + chunk] =
            make_float2(best, __int_as_float(chunk * CHUNK0 + bi));
    } else {
        int bx = blockIdx.x - 256;
        int b = bx >> 1;
        const float4* tp = pt1 + b * N1;
        for (int i = tid; i < N1; i += 256) {
            float4 q = tp[i];
            sm[i] = make_float4(-2.f * q.x, -2.f * q.y, -2.f * q.z, q.w);
        }
        __syncthreads();
        int n = (bx & 1) * 256 + tid;
        float4 p = ps1[b * N1 + n];
        float best = FLT_MAX; int bi = 0;
#pragma unroll 8
        for (int m = 0; m < N1; ++m) {
            float4 q = sm[m];
            float d = fmaf(p.x, q.x, fmaf(p.y, q.y, fmaf(p.z, q.z, q.w)));
            if (d < best) { best = d; bi = m; }
        }
        const float* s = sd1 + (size_t)b * CDESC * N1 + n;
        const float* t = td1 + (size_t)b * CDESC * N1 + bi;
        float num = 0.f, s2 = 0.f, t2 = 0.f;
#pragma unroll
        for (int c = 0; c < CDESC; ++c) {
            float a = s[c * N1], g = t[c * N1];
            num = fmaf(a, g, num); s2 = fmaf(a, a, s2); t2 = fmaf(g, g, t2);
        }
        float denom = fmaxf(sqrtf(s2), 1e-8f) * fmaxf(sqrtf(t2), 1e-8f);
        wave_reduce_atomic(num / denom, acc + 1);
    }
}

// K4: stage-0 chunk combine + descriptor gather + cosine + reduce; last block finalizes.
__global__ void cos0_final(const float2* __restrict__ partial,
                           const float* __restrict__ sd, const float* __restrict__ td,
                           float* __restrict__ acc, float* __restrict__ out) {
    int gid = blockIdx.x * 256 + threadIdx.x;      // 0..16383
    int b = gid >> 12, n = gid & (N0 - 1);
    const float2* pp = partial + (size_t)gid * 4;
    float2 e = pp[0];
    float2 e1 = pp[1]; if (e1.x < e.x) e = e1;     // ascending chunk order + strict <
    float2 e2 = pp[2]; if (e2.x < e.x) e = e2;
    float2 e3 = pp[3]; if (e3.x < e.x) e = e3;
    int nearest = __float_as_int(e.y);
    const float* s = sd + (size_t)b * CDESC * N0 + n;
    const float* t = td + (size_t)b * CDESC * N0 + nearest;
    float num = 0.f, s2 = 0.f, t2 = 0.f;
#pragma unroll
    for (int c = 0; c < CDESC; ++c) {
        float a = s[c * N0], g = t[c * N0];
        num = fmaf(a, g, num); s2 = fmaf(a, a, s2); t2 = fmaf(g, g, t2);
    }
    float denom = fmaxf(sqrtf(s2), 1e-8f) * fmaxf(sqrtf(t2), 1e-8f);
    wave_reduce_atomic(num / denom, acc + 0);

    __syncthreads();                               // all this block's atomics issued
    if (threadIdx.x == 0) {
        __threadfence();                           // make them device-visible
        unsigned old = atomicAdd((unsigned*)(acc + 2), 1u);
        if (old == 63u) {                          // last of 64 blocks
            float a0 = atomicAdd(acc + 0, 0.f);    // coherent reads
            float a1 = atomicAdd(acc + 1, 0.f);    // acc[1] done in prior kernel (stream order)
            out[0] = 1.f - 0.5f * (a0 * (1.f / 16384.f) + a1 * (1.f / 2048.f));
        }
    }
}

extern "C" void kernel_launch(void* const* d_in, const int* in_sizes, int n_in,
                              void* d_out, int out_size, void* d_ws, size_t ws_size,
                              hipStream_t stream) {
    const float* c_src = (const float*)d_in[0];   // [4,3,64,64,64]
    const float* c_tgt = (const float*)d_in[1];
    const float* sd0   = (const float*)d_in[2];   // [4,32,16,16,16]
    const float* td0   = (const float*)d_in[3];
    const float* sd1   = (const float*)d_in[4];   // [4,32,8,8,8]
    const float* td1   = (const float*)d_in[5];
    float* out = (float*)d_out;

    char* ws = (char*)d_ws;
    float*  acc  = (float*)ws;                     // [0]=sum0 [1]=sum1 [2]=ticket [3]=pad
    float*  t16a = (float*)(ws + 256);             // 786432 floats
    float*  t16b = t16a + 786432;
    float*  t8a  = t16b + 786432;                  // 393216 floats
    float*  t8b  = t8a + 393216;
    float4* ps0  = (float4*)(t8b + 393216);        // 16384 float4 (16B-aligned offset)
    float4* pt0  = ps0 + 16384;
    float4* ps1  = pt0 + 16384;                    // 2048 float4
    float4* pt1  = ps1 + 2048;
    float2* part = (float2*)(pt1 + 2048);          // 65536 float2

    pass1_both<<<dim3(4608, 2), 256, 0, stream>>>(c_src, c_tgt, t16a, t16b, t8a, t8b, acc);
    pass2_both<<<dim3(72, 2),   256, 0, stream>>>(t16a, t16b, t8a, t8b, ps0, pt0, ps1, pt1);
    argmin_plus_stage1<<<264, 256, 0, stream>>>(ps0, pt0, part, ps1, pt1, sd1, td1, acc);
    cos0_final<<<64, 256, 0, stream>>>(part, sd0, td0, acc, out);
}